// Round 3
// baseline (7042.924 us; speedup 1.0000x reference)
//
#include <hip/hip_runtime.h>
#include <stdint.h>

// B=32, T=128, DIN=DOUT=1024. Input dtypes detected at runtime (bf16 vs fp32).
typedef unsigned short u16;
typedef __attribute__((ext_vector_type(8))) short short8;   // 8 x bf16 MFMA operand
typedef __attribute__((ext_vector_type(4))) float f32x4;    // MFMA accumulator

// ---- workspace layout (bytes) ----
#define CNT_OFF    0                          // 256 barrier counters
#define FLG_OFF    2048                       // 13 dtype flags
#define H_OFF      4096                       // h fp32: 128 KB
#define HBF_OFF    (H_OFF + 32*1024*4)        // h bf16: 64 KB
#define ZERO_BYTES (HBF_OFF + 32*1024*2)      // memset [0, ZERO_BYTES)
#define RH_OFF     ZERO_BYTES                 // r*h bf16: 64 KB (write-before-read)
#define Z_OFF      (RH_OFF + 32*1024*2)       // z fp32: 128 KB (write-before-read)
#define BS_OFF     (Z_OFF + 32*1024*4)        // bias sums fp32: 3*1024*4
#define XB_OFF     (1<<20)                    // x bf16: 8 MB
#define WB_OFF     (9<<20)                    // 6 weight mats bf16: 12 MB
#define WS_FULL    (21u<<20)
#define WS_NOX     (13u<<20)

__device__ __forceinline__ float bf2f(u16 v) {
    unsigned u = ((unsigned)v) << 16;
    return __builtin_bit_cast(float, u);
}
__device__ __forceinline__ u16 f2bf(float f) {
    unsigned u = __builtin_bit_cast(unsigned, f);
    unsigned r = 0x7fffu + ((u >> 16) & 1u);   // RNE
    return (u16)((u + r) >> 16);
}
__device__ __forceinline__ float sigm(float x) { return 1.0f / (1.0f + __expf(-x)); }

__device__ __forceinline__ short8 cvt8f(const float* f) {
    short8 r;
#pragma unroll
    for (int j = 0; j < 8; j++) r[j] = (short)f2bf(f[j]);
    return r;
}

// Grid barrier, 64 co-resident blocks, agent scope.
__device__ __forceinline__ void gbar(unsigned* c, unsigned nb) {
    __threadfence();
    __syncthreads();
    if (threadIdx.x == 0) {
        __hip_atomic_fetch_add(c, 1u, __ATOMIC_ACQ_REL, __HIP_MEMORY_SCOPE_AGENT);
        while (__hip_atomic_load(c, __ATOMIC_ACQUIRE, __HIP_MEMORY_SCOPE_AGENT) < nb)
            __builtin_amdgcn_s_sleep(1);
    }
    __syncthreads();
    __threadfence();
}

struct Ptrs { const void* p[13]; };

// ---- dtype detector: 1 block per input array; sample 1024 u16s (2 KB, safe
// for the smallest buffer: 1024 elems x >=2 B). bf16 data -> ~100% of u16s
// have exponent field in [100,140] (or exact zero); fp32 data -> ~58%.
__global__ __launch_bounds__(256) void detect_k(Ptrs ps, unsigned* flags) {
    const u16* a = (const u16*)ps.p[blockIdx.x];
    __shared__ int tot;
    if (threadIdx.x == 0) tot = 0;
    __syncthreads();
    int cnt = 0;
    for (int i = threadIdx.x; i < 1024; i += 256) {
        unsigned u = a[i];
        unsigned e = (u >> 7) & 0xFF;
        cnt += (e == 0 || (e >= 100 && e <= 140)) ? 1 : 0;
    }
    atomicAdd(&tot, cnt);
    __syncthreads();
    if (threadIdx.x == 0) flags[blockIdx.x] = (tot >= 920) ? 1u : 0u;
}

struct SPtrs { const void* x; const void* W[6]; const void* b[6]; };
// W order: Wz,Uz,Wr,Ur,Wh,Uh (flags 1,3,5,7,9,11); b pairs (bz,cz),(br,cr),(bh,ch).

__device__ __forceinline__ short8 cvt8any(const void* src, long ei, unsigned isbf) {
    if (isbf) return *(const short8*)((const u16*)src + ei);
    return cvt8f((const float*)src + ei);
}

__global__ __launch_bounds__(256) void stage_k(SPtrs ps, const unsigned* __restrict__ flags,
                                               u16* __restrict__ xb, u16* __restrict__ wb,
                                               float* __restrict__ bs, int do_x) {
    int blk = blockIdx.x, tid = threadIdx.x;
    int xblocks = do_x ? 2048 : 0;
    if (blk < xblocks) {                         // x: 4M elems
        long ei = ((long)blk * 256 + tid) * 8;
        *(short8*)(xb + ei) = cvt8any(ps.x, ei, flags[0]);
    } else if (blk < xblocks + 6 * 512) {        // weights: 1M elems each
        int r = (blk - xblocks) >> 9;
        const int fidx[6] = {1, 3, 5, 7, 9, 11};
        long ei = ((long)((blk - xblocks) & 511) * 256 + tid) * 8;
        *(short8*)(wb + (long)r * 1048576 + ei) = cvt8any(ps.W[r], ei, flags[fidx[r]]);
    } else {                                     // bias sums, 1 block
        const int fb[3] = {2, 6, 10}, fc[3] = {4, 8, 12};
        for (int g = 0; g < 3; g++)
            for (int i = tid; i < 1024; i += 256) {
                float b = flags[fb[g]] ? bf2f(((const u16*)ps.b[2 * g])[i])
                                       : ((const float*)ps.b[2 * g])[i];
                float c = flags[fc[g]] ? bf2f(((const u16*)ps.b[2 * g + 1])[i])
                                       : ((const float*)ps.b[2 * g + 1])[i];
                bs[g * 1024 + i] = b + c;
            }
    }
}

// ---- persistent GRU: 64 blocks x 256 thr ----
// Phase 1: 256 waves = 256 16x16 tiles over z (blk 0..31) / r (blk 32..63);
//   dual K=1024 chains (x@W^T and h@U^T). Phase 2: waves 0-1 rh@Uh^T,
//   waves 2-3 x@Wh^T, combine via LDS, update h, write out.
__global__ __launch_bounds__(256) void gru_rec(
    const void* __restrict__ xbase, int xmode,   // 1: xbase=xb bf16; 0: original x
    const u16* __restrict__ wb, const float* __restrict__ bs,
    float* __restrict__ hbuf, u16* __restrict__ hbf,
    u16* __restrict__ rhbuf, float* __restrict__ zbuf,
    const unsigned* __restrict__ flags,
    unsigned* __restrict__ cnt, void* __restrict__ out)
{
    const int tid  = threadIdx.x;
    const int lane = tid & 63, wave = tid >> 6;
    const int quad = lane >> 4, ln = lane & 15;
    const int blk  = blockIdx.x;
    const unsigned NB = gridDim.x;

    const unsigned xisbf = xmode ? 1u : flags[0];
    const unsigned outbf = flags[0];

    const u16* Wz = wb;                  const u16* Uz = wb + 1048576;
    const u16* Wr = wb + 2 * 1048576;    const u16* Ur = wb + 3 * 1048576;
    const u16* Wh = wb + 4 * 1048576;    const u16* Uh = wb + 5 * 1048576;

    // phase-1 geometry
    const int n0   = blk * 32;
    const int gate = n0 >> 10;                 // 0:z 1:r
    const int nl   = n0 & 1023;
    const u16* U1  = gate ? Ur : Uz;
    const u16* W1  = gate ? Wr : Wz;
    const int mt1  = wave & 1, nt1 = wave >> 1;
    const int b1   = mt1 * 16 + ln;            // A-frag row (batch)
    const int d1   = nl + nt1 * 16 + ln;       // output col / weight row
    const float bias1 = bs[gate * 1024 + d1];
    const u16* u1p = U1 + d1 * 1024 + quad * 8;
    const u16* w1p = W1 + d1 * 1024 + quad * 8;
    const u16* h1p = hbf + b1 * 1024 + quad * 8;
    const long x1o = (long)(b1 * 128) * 1024 + quad * 8;   // + t*1024 per step

    // phase-2 geometry
    const int w2    = wave & 1;
    const bool xsd  = (wave >= 2);
    const int d2    = blk * 16 + ln;
    const float bias2 = bs[2048 + d2];
    const u16* uhp  = Uh + d2 * 1024 + quad * 8;
    const u16* whp  = Wh + d2 * 1024 + quad * 8;
    const int b2    = w2 * 16 + ln;
    const u16* rh2p = rhbuf + b2 * 1024 + quad * 8;
    const long x2o  = (long)(b2 * 128) * 1024 + quad * 8;

    __shared__ float partial[2][64][4];

    for (int t = 0; t < 128; t++) {
        { // ---- phase 1: z or r*h ----
            f32x4 aU = (f32x4){0.f,0.f,0.f,0.f};
            f32x4 aW = (f32x4){0.f,0.f,0.f,0.f};
            const long xo = x1o + (long)t * 1024;
#pragma unroll 4
            for (int k = 0; k < 1024; k += 32) {
                short8 ax = cvt8any(xbase, xo + k, xisbf);
                aW = __builtin_amdgcn_mfma_f32_16x16x32_bf16(
                    ax, *(const short8*)(w1p + k), aW, 0, 0, 0);
                aU = __builtin_amdgcn_mfma_f32_16x16x32_bf16(
                    *(const short8*)(h1p + k), *(const short8*)(u1p + k), aU, 0, 0, 0);
            }
#pragma unroll
            for (int r = 0; r < 4; r++) {
                int brow = mt1 * 16 + quad * 4 + r;   // C/D: row=quad*4+r, col=ln
                float s  = aU[r] + aW[r] + bias1;
                float gv = sigm(s);
                if (gate == 0) zbuf[(brow << 10) + d1] = gv;
                else           rhbuf[(brow << 10) + d1] = f2bf(gv * hbuf[(brow << 10) + d1]);
            }
        }
        gbar(cnt + 2 * t, NB);
        { // ---- phase 2: h_hat + update ----
            f32x4 a2 = (f32x4){0.f,0.f,0.f,0.f};
            if (xsd) {
                const long xo = x2o + (long)t * 1024;
#pragma unroll 4
                for (int k = 0; k < 1024; k += 32) {
                    short8 ax = cvt8any(xbase, xo + k, xisbf);
                    a2 = __builtin_amdgcn_mfma_f32_16x16x32_bf16(
                        ax, *(const short8*)(whp + k), a2, 0, 0, 0);
                }
#pragma unroll
                for (int r = 0; r < 4; r++) partial[w2][lane][r] = a2[r];
            } else {
#pragma unroll 4
                for (int k = 0; k < 1024; k += 32)
                    a2 = __builtin_amdgcn_mfma_f32_16x16x32_bf16(
                        *(const short8*)(rh2p + k), *(const short8*)(uhp + k), a2, 0, 0, 0);
            }
            __syncthreads();
            if (!xsd) {
#pragma unroll
                for (int r = 0; r < 4; r++) {
                    int brow = w2 * 16 + quad * 4 + r;
                    float s  = a2[r] + partial[w2][lane][r] + bias2;
                    float hh = sigm(s);
                    float z  = zbuf[(brow << 10) + d2];
                    float hv = hbuf[(brow << 10) + d2];
                    float hn = (1.0f - z) * hv + z * hh;
                    hbuf[(brow << 10) + d2] = hn;
                    u16 hb = f2bf(hn);
                    hbf[(brow << 10) + d2] = hb;
                    long oi = (((long)(t * 32) + brow) << 10) + d2;  // ys (T,B,D) flat
                    if (outbf) ((u16*)out)[oi] = hb;
                    else       ((float*)out)[oi] = hn;
                }
            }
        }
        if (t < 127) gbar(cnt + 2 * t + 1, NB);
    }
}

extern "C" void kernel_launch(void* const* d_in, const int* in_sizes, int n_in,
                              void* d_out, int out_size, void* d_ws, size_t ws_size,
                              hipStream_t stream)
{
    char* ws = (char*)d_ws;
    hipMemsetAsync(d_ws, 0, ZERO_BYTES, stream);   // counters + flags + h + h_bf16

    unsigned* flags = (unsigned*)(ws + FLG_OFF);
    unsigned* cnt   = (unsigned*)(ws + CNT_OFF);
    float*    hbuf  = (float*)(ws + H_OFF);
    u16*      hbf   = (u16*)(ws + HBF_OFF);
    u16*      rh    = (u16*)(ws + RH_OFF);
    float*    zb    = (float*)(ws + Z_OFF);
    float*    bs    = (float*)(ws + BS_OFF);
    u16*      xb    = (u16*)(ws + XB_OFF);
    u16*      wbuf; // bf16 weights

    Ptrs dp;
    for (int i = 0; i < 13; i++) dp.p[i] = d_in[i];
    detect_k<<<13, 256, 0, stream>>>(dp, flags);

    SPtrs sp;
    sp.x = d_in[0];
    sp.W[0] = d_in[1];  sp.W[1] = d_in[3];   // Wz, Uz
    sp.W[2] = d_in[5];  sp.W[3] = d_in[7];   // Wr, Ur
    sp.W[4] = d_in[9];  sp.W[5] = d_in[11];  // Wh, Uh
    sp.b[0] = d_in[2];  sp.b[1] = d_in[4];   // bz, cz
    sp.b[2] = d_in[6];  sp.b[3] = d_in[8];   // br, cr
    sp.b[4] = d_in[10]; sp.b[5] = d_in[12];  // bh, ch

    if (ws_size >= WS_FULL) {
        wbuf = (u16*)(ws + WB_OFF);
        stage_k<<<2048 + 6 * 512 + 1, 256, 0, stream>>>(sp, flags, xb, wbuf, bs, 1);
        gru_rec<<<64, 256, 0, stream>>>(xb, 1, wbuf, bs, hbuf, hbf, rh, zb, flags, cnt, d_out);
    } else {
        wbuf = (u16*)(ws + XB_OFF);          // no x staging; weights at 1 MB
        stage_k<<<6 * 512 + 1, 256, 0, stream>>>(sp, flags, xb, wbuf, bs, 0);
        gru_rec<<<64, 256, 0, stream>>>(d_in[0], 0, wbuf, bs, hbuf, hbf, rh, zb, flags, cnt, d_out);
    }
}